// Round 7
// baseline (232.651 us; speedup 1.0000x reference)
//
#include <hip/hip_runtime.h>

// CIN cross-network, fused MFMA implementation (f16 inputs, fp32 accum).
// Round 7: 32x32x16 MFMA (R2-verified lane mappings) on top of R4's
// conflict-free layouts. Pipe floor 199K -> 165K cyc/CU; LDS 53.8 -> 49.7 KB
// (possible 3 blocks/CU). No stagger, no inline asm, no explicit pipeline
// (R5/R6 proved those neutral/negative at this occupancy).
//
// y[b,n,d] = relu( sum_{m,h} x0[b,m,d] * xk[b,h,d] * W[m,h,n] )
// out[b, 64*l + n] = sum_d y  (per layer l)
//
// GEMM view per batch-pair: rows i=0..31 (i<16: batch bp*2 d=i; i>=16:
// bp*2+1, d=i-16), cols n (2 tiles of 32), K = m*H + h.
// Per-wave: 4 private batches (2 pairs); all LDS wave-private => NO barriers.

typedef _Float16 half8 __attribute__((ext_vector_type(8)));
typedef _Float16 half2v __attribute__((ext_vector_type(2)));
typedef float f32x16 __attribute__((ext_vector_type(16)));

#define OUT_STRIDE 192
#define X0R 33            // x0 row stride (f16): 66B -> 16-lane column reads
                          // hit 16 banks; 2nd batch-half offset by 8 banks
                          // (264%32) -> <=2-way across 32 lanes = free
#define X0B (16 * X0R)    // 528 f16 per batch
#define XKR 64            // xk row stride: exact (16B-aligned); rare av/epi
                          // ops pay <=4-way, saves 4KB LDS/block
#define XKB 1024          // xk batch stride

// ---------------------------------------------------------------------------
// Weight repack: fp32 W[k=(m*H+h)][n] -> f16 32x32x16 fragment order,
// contiguous per 16-k block:
//   dst[((kb*2 + t)*64 + lane)*8 + j] = W[k*64 + n],
//   k = kb*16 + (lane>>5)*8 + j,  n = t*32 + (lane&31)
// Each block handles 2 kb blocks = one contiguous 8KB source tile.
__global__ void prep_w_all(const float* __restrict__ W0,
                           const float* __restrict__ W1,
                           const float* __restrict__ W2,
                           _Float16* __restrict__ dst) {
  __shared__ float tile[32 * 65];
  const int tid = threadIdx.x;
  const int blk = blockIdx.x;
  const float* src;
  _Float16* d;
  int bl;
  if (blk < 32)      { src = W0; d = dst;          bl = blk; }
  else if (blk < 96) { src = W1; d = dst + 65536;  bl = blk - 32; }
  else               { src = W2; d = dst + 196608; bl = blk - 96; }
  src += (size_t)bl * 2048;
  d   += (size_t)bl * 2048;
#pragma unroll
  for (int i = tid; i < 2048; i += 256)
    tile[(i >> 6) * 65 + (i & 63)] = src[i];
  __syncthreads();
  const int sub  = tid >> 7;         // which kb16 within the 8KB tile
  const int t    = (tid >> 6) & 1;   // n-tile of 32
  const int lane = tid & 63;
  const int q2 = lane >> 5, l31 = lane & 31;
  half8 v;
#pragma unroll
  for (int j = 0; j < 8; ++j)
    v[j] = (_Float16)tile[(sub * 16 + q2 * 8 + j) * 65 + t * 32 + l31];
  *(half8*)(d + ((sub * 2 + t) * 64 + lane) * 8) = v;
}

// ---------------------------------------------------------------------------
// One layer for one wave's 4 private batches (2 pairs along M=32).
// NHB: 16-wide h-blocks (2 for H=32, 4 for H=64). av[bp][hb] in registers:
// av[bp][hb][j] = xk[bl, h = hb*16 + (lane>>5)*8 + j, d = lane&15].
// xsb[bp] -> x0 row base for this lane's batch (bl = bp*2 + ((lane>>4)&1)).
template<int NHB, bool LAST>
__device__ __forceinline__ void run_layer(
    const _Float16* __restrict__ Wp, const half8 (&av)[2][NHB],
    const _Float16* const (&xsb)[2], _Float16* xkw, float* __restrict__ out,
    long gb0, int loff, int lane)
{
  const int q2 = lane >> 5, l31 = lane & 31;

  f32x16 acc[2][2];
#pragma unroll
  for (int bp = 0; bp < 2; ++bp)
#pragma unroll
    for (int t = 0; t < 2; ++t)
#pragma unroll
      for (int g = 0; g < 16; ++g) acc[bp][t][g] = 0.f;

  const _Float16* Wl = Wp + lane * 8;

#pragma unroll 2
  for (int m = 0; m < 32; ++m) {
    half2v xs2[2];
#pragma unroll
    for (int bp = 0; bp < 2; ++bp) {
      _Float16 x = xsb[bp][m];
      xs2[bp] = (half2v){x, x};
    }
#pragma unroll
    for (int hb = 0; hb < NHB; ++hb) {
      const int kb = m * NHB + hb;
      const _Float16* p = Wl + (size_t)kb * 1024;
      half8 B0 = *(const half8*)(p);         // n-tile 0, +0B
      half8 B1 = *(const half8*)(p + 512);   // n-tile 1, +1024B immediate
#pragma unroll
      for (int bp = 0; bp < 2; ++bp) {
        half8 af;
        half2v* ap = (half2v*)&af;
        const half2v* vp = (const half2v*)&av[bp][hb];
#pragma unroll
        for (int j2 = 0; j2 < 4; ++j2) ap[j2] = vp[j2] * xs2[bp];
        acc[bp][0] = __builtin_amdgcn_mfma_f32_32x32x16_f16(af, B0, acc[bp][0], 0, 0, 0);
        acc[bp][1] = __builtin_amdgcn_mfma_f32_32x32x16_f16(af, B1, acc[bp][1], 0, 0, 0);
      }
    }
  }

  // Epilogue (R2-verified). C/D: col n = lane&31, row = (g&3)+8*(g>>2)+4*q2;
  // g<8 -> batch half 0, g>=8 -> half 1; d = row&15.
#pragma unroll
  for (int bp = 0; bp < 2; ++bp) {
#pragma unroll
    for (int t = 0; t < 2; ++t) {
      float s[2] = {0.f, 0.f};
#pragma unroll
      for (int g = 0; g < 16; ++g) {
        float v = acc[bp][t][g];
        v = v > 0.f ? v : 0.f;
        const int half = g >> 3;
        const int g7 = g & 7;
        const int d = (g7 & 3) + 8 * (g7 >> 2) + 4 * q2;
        s[half] += v;
        if (!LAST)
          xkw[(bp * 2 + half) * XKB + d * XKR + t * 32 + l31] = (_Float16)v;
      }
      s[0] += __shfl_xor(s[0], 32);
      s[1] += __shfl_xor(s[1], 32);
      const float sv = q2 ? s[1] : s[0];
      out[(gb0 + bp * 2 + q2) * OUT_STRIDE + loff + t * 32 + l31] = sv;
    }
  }
}

__global__ __launch_bounds__(256, 3) void cin_main(
    const float* __restrict__ emb, const _Float16* __restrict__ Wall,
    float* __restrict__ out)
{
  // x0: 16 batches * 528 f16 = 16896 B;  xk: 16 * 1024 f16 = 32768 B.
  // Total 49664 B/block -> 3 blocks/CU if LDS granularity permits.
  __shared__ __align__(16) _Float16 lds[16 * X0B + 16 * XKB];
  const int lane = threadIdx.x & 63;
  const int wv = threadIdx.x >> 6;
  const int r16 = lane & 15;
  const int q2 = lane >> 5;
  const int bhalf = (lane >> 4) & 1;
  const long gb0 = (long)blockIdx.x * 16 + wv * 4;

  _Float16* x0w = &lds[wv * 4 * X0B];
  _Float16* xkw = &lds[16 * X0B + wv * 4 * XKB];

  // Stage this wave's 4 batches: read (m,d) fp32, write transposed (d,m) f16.
#pragma unroll
  for (int bb = 0; bb < 4; ++bb) {
    const float* src = emb + (gb0 + bb) * 512;
    _Float16* dstb = x0w + bb * X0B;
#pragma unroll
    for (int i = 0; i < 2; ++i) {
      int f = i * 256 + lane * 4;         // flat = m*16 + d, d aligned to 4
      float4 v = *(const float4*)(src + f);
      int m = f >> 4, d = f & 15;
      dstb[(d + 0) * X0R + m] = (_Float16)v.x;
      dstb[(d + 1) * X0R + m] = (_Float16)v.y;
      dstb[(d + 2) * X0R + m] = (_Float16)v.z;
      dstb[(d + 3) * X0R + m] = (_Float16)v.w;
    }
  }
  // All LDS regions are wave-private: program order + waitcnt suffice.

  // Lane-resolved x0 row bases (batch bl = bp*2 + bhalf).
  const _Float16* xsb[2] = {
    x0w + (0 + bhalf) * X0B + r16 * X0R,
    x0w + (2 + bhalf) * X0B + r16 * X0R,
  };

  // Layer 1: A-vectors from x0 (h-range 0..31 -> NHB=2); stride-33 rows are
  // only 2B-aligned so build with scalar reads (one-time).
  half8 av1[2][2];
#pragma unroll
  for (int bp = 0; bp < 2; ++bp)
#pragma unroll
    for (int hb = 0; hb < 2; ++hb)
#pragma unroll
      for (int j = 0; j < 8; ++j)
        av1[bp][hb][j] = xsb[bp][hb * 16 + q2 * 8 + j];
  run_layer<2, false>(Wall, av1, xsb, xkw, out, gb0, 0, lane);

  // Layer 2: A-vectors from xk (h = hb*16 + q2*8 + j), 16B-aligned b128.
  half8 av2[2][4];
#pragma unroll
  for (int bp = 0; bp < 2; ++bp)
#pragma unroll
    for (int hb = 0; hb < 4; ++hb)
      av2[bp][hb] = *(const half8*)(xkw + (bp * 2 + bhalf) * XKB +
                                    r16 * XKR + hb * 16 + q2 * 8);
  run_layer<4, false>(Wall + 65536, av2, xsb, xkw, out, gb0, 64, lane);

  // Layer 3: reload A-vectors (layer 2 rewrote xk).
#pragma unroll
  for (int bp = 0; bp < 2; ++bp)
#pragma unroll
    for (int hb = 0; hb < 4; ++hb)
      av2[bp][hb] = *(const half8*)(xkw + (bp * 2 + bhalf) * XKB +
                                    r16 * XKR + hb * 16 + q2 * 8);
  run_layer<4, true>(Wall + 196608, av2, xsb, xkw, out, gb0, 128, lane);
}

extern "C" void kernel_launch(void* const* d_in, const int* in_sizes, int n_in,
                              void* d_out, int out_size, void* d_ws, size_t ws_size,
                              hipStream_t stream) {
  const float* emb = (const float*)d_in[0];
  const float* W0  = (const float*)d_in[1];
  const float* W1  = (const float*)d_in[2];
  const float* W2  = (const float*)d_in[3];
  float* out = (float*)d_out;
  _Float16* ws = (_Float16*)d_ws;   // needs 327680 f16 = 640 KB

  // Weight repack: one block per 8KB source tile (2 kb16 blocks): 160 blocks.
  prep_w_all<<<160, 256, 0, stream>>>(W0, W1, W2, ws);

  // 16384 batches / 16 per block = 1024 blocks of 256 threads (4 waves x 4 b).
  cin_main<<<1024, 256, 0, stream>>>(emb, ws, out);
}